// Round 6
// baseline (139.952 us; speedup 1.0000x reference)
//
#include <hip/hip_runtime.h>
#include <hip/hip_bf16.h>

#define BB 4096
#define SS 128
#define DIMQ 512
#define DIMZ 64
#define HIDV 512

typedef __attribute__((ext_vector_type(8))) short sh8;
typedef __attribute__((ext_vector_type(4))) float f32x4;

__device__ inline unsigned short f2bf(float f) {
    unsigned u = __float_as_uint(f);
    return (unsigned short)((u + 0x7fffu + ((u >> 16) & 1u)) >> 16);
}

// LDS-free GEMM tile: 64 rows x 128 cols per block (4 waves, each 32x64).
// A fragments loaded per-lane from f32 source (cvt->bf16 in regs), B from
// L2-resident W1qT bf16. Epilogue: tanh(acc+c)*W2 row-reduce -> atomicAdd.
__device__ __forceinline__ void gemm_tile(
        int gi, bool isE1, const float* __restrict__ A0, const float* __restrict__ A1,
        float R00, float R01,
        const unsigned short* __restrict__ W1qT, const float* __restrict__ cvec,
        const float* __restrict__ W2, float* __restrict__ tgt, int tgtMode, int t) {
    const int lane = t & 63;
    const int w = t >> 6;
    const int rowBase = (gi >> 2) * 64 + (w >> 1) * 32;
    const int colBase = (gi & 3) * 128 + (w & 1) * 64;
    const int rr = lane & 15, g = lane >> 4;

    f32x4 acc[2][4] = {};
    for (int kt = 0; kt < 16; kt++) {
        sh8 af[2];
        #pragma unroll
        for (int mi = 0; mi < 2; mi++) {
            const float* pa = A0 + (size_t)(rowBase + mi * 16 + rr) * 512 + kt * 32 + g * 8;
            float4 x0 = *(const float4*)pa;
            float4 x1 = *(const float4*)(pa + 4);
            if (isE1) {
                const float* pb = A1 + (size_t)(rowBase + mi * 16 + rr) * 512 + kt * 32 + g * 8;
                float4 y0 = *(const float4*)pb;
                float4 y1 = *(const float4*)(pb + 4);
                #pragma unroll
                for (int j = 0; j < 4; j++) {
                    x0[j] = R00 * x0[j] + R01 * y0[j];
                    x1[j] = R00 * x1[j] + R01 * y1[j];
                }
            }
            sh8 v;
            #pragma unroll
            for (int j = 0; j < 4; j++) {
                v[j] = (short)f2bf(x0[j]);
                v[4 + j] = (short)f2bf(x1[j]);
            }
            af[mi] = v;
        }
        sh8 bf_[4];
        #pragma unroll
        for (int ni = 0; ni < 4; ni++)
            bf_[ni] = *(const sh8*)(W1qT + (size_t)(colBase + ni * 16 + rr) * 512 + kt * 32 + g * 8);
        #pragma unroll
        for (int mi = 0; mi < 2; mi++)
            #pragma unroll
            for (int ni = 0; ni < 4; ni++)
                acc[mi][ni] = __builtin_amdgcn_mfma_f32_16x16x32_bf16(af[mi], bf_[ni], acc[mi][ni], 0, 0, 0);
    }
    float w2v[4], cv[4];
    #pragma unroll
    for (int ni = 0; ni < 4; ni++) {
        int n = colBase + ni * 16 + rr;
        w2v[ni] = W2[n];
        cv[ni] = cvec[n];
    }
    #pragma unroll
    for (int mi = 0; mi < 2; mi++) {
        #pragma unroll
        for (int r = 0; r < 4; r++) {
            float s = 0.f;
            #pragma unroll
            for (int ni = 0; ni < 4; ni++)
                s += tanhf(acc[mi][ni][r] + cv[ni]) * w2v[ni];
            s += __shfl_xor(s, 1, 64);
            s += __shfl_xor(s, 2, 64);
            s += __shfl_xor(s, 4, 64);
            s += __shfl_xor(s, 8, 64);
            if (rr == 0) {
                int row = rowBase + mi * 16 + g * 4 + r;
                if (tgtMode == 0) atomicAdd(tgt + row, s);
                else atomicAdd(tgt + (size_t)row * 2, s);
            }
        }
    }
}

// Prep: W1qT[n][k]=bf16(W1[k][n]) k<512; cvec = b1 + z@W1[512:576]; zero Vnet.
__global__ __launch_bounds__(256) void k_prep(const float* __restrict__ W1,
        const float* __restrict__ z, const float* __restrict__ b1,
        unsigned short* __restrict__ W1qT, float* __restrict__ cvec,
        float* __restrict__ Vnet) {
    __shared__ float tile[32][33];
    int bx = blockIdx.x & 15, by = blockIdx.x >> 4;
    int k0 = by * 32, n0 = bx * 32;
    int tx = threadIdx.x & 31, tg = threadIdx.x >> 5;
    #pragma unroll
    for (int rr = 0; rr < 4; rr++) {
        int ty = tg * 4 + rr;
        tile[ty][tx] = W1[(size_t)(k0 + ty) * HIDV + n0 + tx];
    }
    __syncthreads();
    #pragma unroll
    for (int rr = 0; rr < 4; rr++) {
        int ty = tg * 4 + rr;
        W1qT[(size_t)(n0 + ty) * DIMQ + k0 + tx] = f2bf(tile[tx][ty]);
    }
    if (blockIdx.x < 2) {
        int h = blockIdx.x * 256 + threadIdx.x;
        float acc = b1[h];
        #pragma unroll 8
        for (int k = 0; k < DIMZ; k++) acc += z[k] * W1[(size_t)(DIMQ + k) * HIDV + h];
        cvec[h] = acc;
    }
    if (blockIdx.x < 12) {
        int i = blockIdx.x * 1024 + threadIdx.x * 4;
        float4 zv = {0.f, 0.f, 0.f, 0.f};
        *(float4*)(Vnet + i) = zv;
    }
}

// K1: 2048 scan blocks + 768 LDS-free GEMM blocks (e0/e1/e2 -> Vnet),
// uniformly interleaved in dispatch order; VGPR capped for scan occupancy.
__global__ __launch_bounds__(256, 4) void k_main(
        const float* __restrict__ u, const float* __restrict__ q0off,
        const float* __restrict__ p0off, const float* __restrict__ q0on,
        const float* __restrict__ p0on, const float* __restrict__ b2,
        const unsigned short* __restrict__ W1qT, const float* __restrict__ cvec,
        const float* __restrict__ W2, float* __restrict__ Vnet,
        float* __restrict__ out, float* __restrict__ qtraj,
        float R00, float R01, float R10, float R11) {
    const int t = threadIdx.x;
    const int bid = blockIdx.x;
    const int g1 = (int)(((long)bid * 768) / 2816);
    const int g2 = (int)(((long)(bid + 1) * 768) / 2816);
    if (g2 > g1) {
        int e = g1 >> 8, gi = g1 & 255;
        gemm_tile(gi, e == 1, (e == 2) ? q0on : q0off, p0off, R00, R01,
                  W1qT, cvec, W2, Vnet + e * BB, 0, t);
        return;
    }

    // ---------------- scan path ----------------
    int sb = bid - g1;
    int half = t >> 7;
    int tc = t & 127;
    int b = sb * 2 + half;
    int j = tc * 4;
    size_t idx = (size_t)b * DIMQ + j;
    float q[4], p[4], qo[4], po[4];
    *(float4*)q  = *(const float4*)(q0off + idx);
    *(float4*)p  = *(const float4*)(p0off + idx);
    *(float4*)qo = *(const float4*)(q0on + idx);
    *(float4*)po = *(const float4*)(p0on + idx);

    float sums[8] = {0, 0, 0, 0, 0, 0, 0, 0};
    float q2[4], p2[4];
    #pragma unroll
    for (int c = 0; c < 4; c++) {
        float qq = q[c], pp = p[c];
        sums[0] += qq * qq;
        sums[1] += pp * pp;
        float qf = R00 * qq + R01 * pp;
        float pf = R10 * qq + R11 * pp;
        sums[2] += qf * qf;
        sums[3] += pf * pf;
        q2[c] = qo[c]; p2[c] = po[c];
        sums[4] += q2[c] * q2[c];
        sums[5] += p2[c] * p2[c];
    }
    const float* ub = u + (size_t)b * SS * DIMQ + j;
    #pragma unroll
    for (int st = 0; st < 10; st++) {
        float uv[4];
        *(float4*)uv = *(const float4*)(ub + (size_t)st * DIMQ);
        #pragma unroll
        for (int c = 0; c < 4; c++) {
            p2[c] = (p2[c] - 0.1f * (0.1f * q2[c]) + 0.1f * (0.1f * uv[c])) * 0.99f;
            q2[c] = q2[c] + 0.1f * p2[c];
        }
    }
    #pragma unroll
    for (int c = 0; c < 4; c++) {
        sums[6] += q2[c] * q2[c];
        sums[7] += p2[c] * p2[c];
    }
    *(float4*)(qtraj + idx) = *(float4*)q2;

    __shared__ float red[32];   // [2][2][8]
    int lane = t & 63, wv = (t >> 6) & 1;
    #pragma unroll
    for (int k = 0; k < 8; k++) {
        float v = sums[k];
        #pragma unroll
        for (int m = 1; m < 64; m <<= 1) v += __shfl_xor(v, m, 64);
        if (lane == 0) red[(half * 2 + wv) * 8 + k] = v;
    }
    __syncthreads();
    if (tc < 4) {
        int e = tc;
        float sq = red[(half * 2) * 8 + 2 * e] + red[(half * 2 + 1) * 8 + 2 * e];
        float sp = red[(half * 2) * 8 + 2 * e + 1] + red[(half * 2 + 1) * 8 + 2 * e + 1];
        float F = 0.5f * sp + 0.05f * sq + b2[0];
        size_t o = (size_t)b * 2 + (e & 1) + (size_t)(e >> 1) * 2 * BB;
        out[o] = F;
    }
}

// K2: blocks 0..255 = e3 GEMM (A=qtraj f32, L3-hot) atomicAdd onto out e3 base;
//     blocks 256..303 = finalize out[e012] += Vnet.
__global__ __launch_bounds__(256) void k_tail(
        const float* __restrict__ qtraj, const unsigned short* __restrict__ W1qT,
        const float* __restrict__ cvec, const float* __restrict__ W2,
        const float* __restrict__ Vnet, float* __restrict__ out) {
    const int t = threadIdx.x;
    if (blockIdx.x >= 256) {
        int i = (blockIdx.x - 256) * 256 + t;   // 0..12287
        int e = i >> 12, b = i & 4095;
        size_t o = (size_t)b * 2 + (e & 1) + (size_t)(e >> 1) * 2 * BB;
        out[o] += Vnet[i];
        return;
    }
    gemm_tile(blockIdx.x, false, qtraj, nullptr, 0.f, 0.f,
              W1qT, cvec, W2, out + 2 * BB + 1, 1, t);
}

extern "C" void kernel_launch(void* const* d_in, const int* in_sizes, int n_in,
                              void* d_out, int out_size, void* d_ws, size_t ws_size,
                              hipStream_t stream) {
    const float* u     = (const float*)d_in[0];
    const float* q0off = (const float*)d_in[1];
    const float* p0off = (const float*)d_in[2];
    const float* q0on  = (const float*)d_in[3];
    const float* p0on  = (const float*)d_in[4];
    const float* z     = (const float*)d_in[5];
    const float* W1    = (const float*)d_in[6];
    const float* b1    = (const float*)d_in[7];
    const float* W2    = (const float*)d_in[8];
    const float* b2    = (const float*)d_in[9];
    float* out = (float*)d_out;
    float* qtraj = out + 4 * BB;

    char* ws = (char*)d_ws;
    unsigned short* W1qT = (unsigned short*)ws;        // 512 KB
    float* cvec = (float*)(ws + 524288);               // 2 KB
    float* Vnet = (float*)(ws + 524288 + 2048);        // 48 KB (12288 f32)

    // offline propagator M^19 (double): q' = q + 0.1 p ; p' = 0.99 p - 0.0099 q
    double a00 = 1, a01 = 0, a10 = 0, a11 = 1;
    const double m00 = 1.0, m01 = 0.1, m10 = -0.1 * 0.1 * 0.99, m11 = 0.99;
    for (int i = 0; i < 19; i++) {
        double n00 = m00 * a00 + m01 * a10;
        double n01 = m00 * a01 + m01 * a11;
        double n10 = m10 * a00 + m11 * a10;
        double n11 = m10 * a01 + m11 * a11;
        a00 = n00; a01 = n01; a10 = n10; a11 = n11;
    }

    k_prep<<<256, 256, 0, stream>>>(W1, z, b1, W1qT, cvec, Vnet);
    k_main<<<2816, 256, 0, stream>>>(u, q0off, p0off, q0on, p0on, b2,
                                     W1qT, cvec, W2, Vnet, out, qtraj,
                                     (float)a00, (float)a01, (float)a10, (float)a11);
    k_tail<<<304, 256, 0, stream>>>(qtraj, W1qT, cvec, W2, Vnet, out);
}

// Round 7
// 47.516 us; speedup vs baseline: 2.9453x; 2.9453x over previous
//
#include <hip/hip_runtime.h>
#include <hip/hip_bf16.h>

#define BB 4096
#define SS 128
#define DIMQ 512
#define DIMZ 64
#define HIDV 512

typedef __attribute__((ext_vector_type(8))) short sh8;
typedef __attribute__((ext_vector_type(4))) float f32x4;
typedef __attribute__((ext_vector_type(4))) unsigned short us4;

__device__ inline unsigned short f2bf(float f) {
    unsigned u = __float_as_uint(f);
    return (unsigned short)((u + 0x7fffu + ((u >> 16) & 1u)) >> 16);
}

__device__ __forceinline__ float fast_tanh(float x) {
    float e = __expf(2.0f * x);                     // v_mul + v_exp
    return 1.0f - 2.0f * __builtin_amdgcn_rcpf(e + 1.0f);
}

// Blocks 0..2047: states for batches 2b, 2b+1 (128 threads per row).
// Blocks 2048..2303: prep (W1 transpose->bf16, cvec) -- consumed only by k_gemm.
__global__ __launch_bounds__(256) void k_states_prep(
        const float* __restrict__ u, const float* __restrict__ q0off,
        const float* __restrict__ p0off, const float* __restrict__ q0on,
        const float* __restrict__ p0on, const float* __restrict__ b2,
        const float* __restrict__ W1, const float* __restrict__ z,
        const float* __restrict__ b1,
        unsigned short* __restrict__ Qall, unsigned short* __restrict__ W1qT,
        float* __restrict__ cvec, float* __restrict__ out,
        float* __restrict__ qtraj,
        float R00, float R01, float R10, float R11) {
    if (blockIdx.x >= 2048) {
        // ---- prep path ----
        int pbi = blockIdx.x - 2048;
        __shared__ float tile[32][33];
        int bx = pbi & 15, by = pbi >> 4;
        int k0 = by * 32, n0 = bx * 32;
        int tx = threadIdx.x & 31, tg = threadIdx.x >> 5;
        #pragma unroll
        for (int rr = 0; rr < 4; rr++) {
            int ty = tg * 4 + rr;
            tile[ty][tx] = W1[(size_t)(k0 + ty) * HIDV + n0 + tx];
        }
        __syncthreads();
        #pragma unroll
        for (int rr = 0; rr < 4; rr++) {
            int ty = tg * 4 + rr;
            W1qT[(size_t)(n0 + ty) * DIMQ + k0 + tx] = f2bf(tile[tx][ty]);
        }
        if (pbi < 2) {
            int h = pbi * 256 + threadIdx.x;
            float acc = b1[h];
            #pragma unroll 8
            for (int k = 0; k < DIMZ; k++) acc += z[k] * W1[(size_t)(DIMQ + k) * HIDV + h];
            cvec[h] = acc;
        }
        return;
    }
    // ---- states path ----
    int t = threadIdx.x;
    int half = t >> 7;           // which batch row of the pair
    int tc = t & 127;
    int b = blockIdx.x * 2 + half;
    int j = tc * 4;
    size_t idx = (size_t)b * DIMQ + j;
    float q[4], p[4], qo[4], po[4];
    *(float4*)q  = *(const float4*)(q0off + idx);
    *(float4*)p  = *(const float4*)(p0off + idx);
    *(float4*)qo = *(const float4*)(q0on + idx);
    *(float4*)po = *(const float4*)(p0on + idx);

    float sums[8] = {0, 0, 0, 0, 0, 0, 0, 0};
    us4 w0, w1, w2, w3;
    float q2[4], p2[4];
    #pragma unroll
    for (int c = 0; c < 4; c++) {
        float qq = q[c], pp = p[c];
        sums[0] += qq * qq;
        sums[1] += pp * pp;
        float qf = R00 * qq + R01 * pp;
        float pf = R10 * qq + R11 * pp;
        sums[2] += qf * qf;
        sums[3] += pf * pf;
        w0[c] = f2bf(qq);
        w1[c] = f2bf(qf);
        q2[c] = qo[c]; p2[c] = po[c];
        sums[4] += q2[c] * q2[c];
        sums[5] += p2[c] * p2[c];
        w2[c] = f2bf(q2[c]);
    }
    *(us4*)(Qall + idx) = w0;
    *(us4*)(Qall + (size_t)(BB + b) * DIMQ + j) = w1;
    *(us4*)(Qall + (size_t)(2 * BB + b) * DIMQ + j) = w2;

    const float* ub = u + (size_t)b * SS * DIMQ + j;
    #pragma unroll
    for (int st = 0; st < 10; st++) {
        float uv[4];
        *(float4*)uv = *(const float4*)(ub + (size_t)st * DIMQ);
        #pragma unroll
        for (int c = 0; c < 4; c++) {
            p2[c] = (p2[c] - 0.1f * (0.1f * q2[c]) + 0.1f * (0.1f * uv[c])) * 0.99f;
            q2[c] = q2[c] + 0.1f * p2[c];
        }
    }
    #pragma unroll
    for (int c = 0; c < 4; c++) {
        sums[6] += q2[c] * q2[c];
        sums[7] += p2[c] * p2[c];
        w3[c] = f2bf(q2[c]);
    }
    *(us4*)(Qall + (size_t)(3 * BB + b) * DIMQ + j) = w3;
    *(float4*)(qtraj + idx) = *(float4*)q2;

    __shared__ float red[2][2][8];
    int lane = t & 63, wv = (t >> 6) & 1;
    #pragma unroll
    for (int k = 0; k < 8; k++) {
        float v = sums[k];
        #pragma unroll
        for (int m = 1; m < 64; m <<= 1) v += __shfl_xor(v, m, 64);
        if (lane == 0) red[half][wv][k] = v;
    }
    __syncthreads();
    if (tc < 4) {
        int e = tc;
        float sq = red[half][0][2 * e] + red[half][1][2 * e];
        float sp = red[half][0][2 * e + 1] + red[half][1][2 * e + 1];
        float F = 0.5f * sp + 0.05f * sq + b2[0];
        size_t o = (size_t)b * 2 + (e & 1) + (size_t)(e >> 1) * 2 * BB;
        out[o] = F;  // GEMM atomicAdds V_net partials on top
    }
}

// GEMM: Qall(16384x512 bf16) @ W1qT^T with fused fast_tanh(.+c)*W2 reduce
// epilogue -> atomicAdd into out. 128x128 tile, 512 threads (8 waves 2x4),
// 3-buffer ring LDS, prefetch distance 2, counted vmcnt (never drains in loop).
__global__ __launch_bounds__(512) void k_gemm(
        const unsigned short* __restrict__ Qall, const unsigned short* __restrict__ W1qT,
        const float* __restrict__ cvec, const float* __restrict__ W2,
        float* __restrict__ out) {
    extern __shared__ char lds[];   // 3 x 32768 (A 16K + B 16K per buffer)
    const int t = threadIdx.x;
    const int lane = t & 63;
    const int g = lane >> 4, rr = lane & 15;
    const int w = t >> 6;
    const int wr = w >> 2, wc = w & 3;       // 2 x 4 waves, each 64 rows x 32 cols
    const int rowBase = blockIdx.x * 128;
    const int colBase = blockIdx.y * 128;

    f32x4 acc[4][2] = {};

    auto STAGE = [&](int kt, int buf) {
        char* ldsA = lds + buf * 32768;
        char* ldsB = ldsA + 16384;
        #pragma unroll
        for (int i = 0; i < 2; i++) {
            unsigned chunk = i * 512 + t;      // 0..1023, 16B each
            unsigned r = chunk >> 3;           // row 0..127
            unsigned scb = (chunk & 7) ^ (r & 7);
            const unsigned short* srcA = Qall + (size_t)(rowBase + r) * 512 + (unsigned)kt * 64 + scb * 8;
            __builtin_amdgcn_global_load_lds(
                (const __attribute__((address_space(1))) unsigned int*)(const void*)srcA,
                (__attribute__((address_space(3))) unsigned int*)(void*)(ldsA + chunk * 16), 16, 0, 0);
            const unsigned short* srcB = W1qT + (size_t)(colBase + r) * 512 + (unsigned)kt * 64 + scb * 8;
            __builtin_amdgcn_global_load_lds(
                (const __attribute__((address_space(1))) unsigned int*)(const void*)srcB,
                (__attribute__((address_space(3))) unsigned int*)(void*)(ldsB + chunk * 16), 16, 0, 0);
        }
    };

    STAGE(0, 0);
    STAGE(1, 1);
    asm volatile("s_waitcnt vmcnt(4)" ::: "memory");   // buf0 ready; buf1 in flight
    __builtin_amdgcn_s_barrier();

    for (int kt = 0; kt < 8; kt++) {
        if (kt < 6) {
            STAGE(kt + 2, (kt + 2) % 3);
            asm volatile("s_waitcnt vmcnt(8)" ::: "memory");   // buf[kt%3] ready; 2 stages in flight
        } else if (kt == 6) {
            asm volatile("s_waitcnt vmcnt(4)" ::: "memory");   // stage6 done; stage7 in flight
        } else {
            asm volatile("s_waitcnt vmcnt(0)" ::: "memory");   // stage7 done
        }
        char* ldsA = lds + (kt % 3) * 32768;
        char* ldsB = ldsA + 16384;
        #pragma unroll
        for (int ks = 0; ks < 2; ks++) {
            sh8 af[4], bf_[2];
            int kb = ks * 64 + (g << 4);
            #pragma unroll
            for (int mi = 0; mi < 4; mi++) {
                int m = wr * 64 + mi * 16 + rr;
                af[mi] = *(const sh8*)(ldsA + m * 128 + (kb ^ ((m & 7) << 4)));
            }
            #pragma unroll
            for (int ni = 0; ni < 2; ni++) {
                int n = wc * 32 + ni * 16 + rr;
                bf_[ni] = *(const sh8*)(ldsB + n * 128 + (kb ^ ((n & 7) << 4)));
            }
            #pragma unroll
            for (int mi = 0; mi < 4; mi++)
                #pragma unroll
                for (int ni = 0; ni < 2; ni++)
                    acc[mi][ni] = __builtin_amdgcn_mfma_f32_16x16x32_bf16(af[mi], bf_[ni], acc[mi][ni], 0, 0, 0);
        }
        asm volatile("s_waitcnt lgkmcnt(0)" ::: "memory");
        __builtin_amdgcn_s_barrier();
    }

    // epilogue: out[row] += sum_n fast_tanh(acc + c[n]) * W2[n]
    float w2v[2], cv[2];
    #pragma unroll
    for (int ni = 0; ni < 2; ni++) {
        int n = colBase + wc * 32 + ni * 16 + rr;
        w2v[ni] = W2[n];
        cv[ni] = cvec[n];
    }
    #pragma unroll
    for (int mi = 0; mi < 4; mi++) {
        #pragma unroll
        for (int r = 0; r < 4; r++) {
            float partial = 0.f;
            #pragma unroll
            for (int ni = 0; ni < 2; ni++)
                partial += fast_tanh(acc[mi][ni][r] + cv[ni]) * w2v[ni];
            partial += __shfl_xor(partial, 1, 64);
            partial += __shfl_xor(partial, 2, 64);
            partial += __shfl_xor(partial, 4, 64);
            partial += __shfl_xor(partial, 8, 64);
            if (rr == 0) {
                int row = rowBase + wr * 64 + mi * 16 + g * 4 + r;
                int e = row >> 12, bb = row & 4095;
                size_t o = (size_t)bb * 2 + (e & 1) + (size_t)(e >> 1) * 2 * BB;
                atomicAdd(out + o, partial);
            }
        }
    }
}

extern "C" void kernel_launch(void* const* d_in, const int* in_sizes, int n_in,
                              void* d_out, int out_size, void* d_ws, size_t ws_size,
                              hipStream_t stream) {
    const float* u     = (const float*)d_in[0];
    const float* q0off = (const float*)d_in[1];
    const float* p0off = (const float*)d_in[2];
    const float* q0on  = (const float*)d_in[3];
    const float* p0on  = (const float*)d_in[4];
    const float* z     = (const float*)d_in[5];
    const float* W1    = (const float*)d_in[6];
    const float* b1    = (const float*)d_in[7];
    const float* W2    = (const float*)d_in[8];
    const float* b2    = (const float*)d_in[9];
    float* out = (float*)d_out;

    char* ws = (char*)d_ws;
    unsigned short* Qall = (unsigned short*)ws;                // 16 MB
    unsigned short* W1qT = (unsigned short*)(ws + 16777216);   // 512 KB
    float* cvec = (float*)(ws + 16777216 + 524288);            // 2 KB

    // offline propagator M^19 (double): q' = q + 0.1 p ; p' = 0.99 p - 0.0099 q
    double a00 = 1, a01 = 0, a10 = 0, a11 = 1;
    const double m00 = 1.0, m01 = 0.1, m10 = -0.1 * 0.1 * 0.99, m11 = 0.99;
    for (int i = 0; i < 19; i++) {
        double n00 = m00 * a00 + m01 * a10;
        double n01 = m00 * a01 + m01 * a11;
        double n10 = m10 * a00 + m11 * a10;
        double n11 = m10 * a01 + m11 * a11;
        a00 = n00; a01 = n01; a10 = n10; a11 = n11;
    }

    k_states_prep<<<2304, 256, 0, stream>>>(u, q0off, p0off, q0on, p0on, b2,
                                            W1, z, b1, Qall, W1qT, cvec, out,
                                            out + 4 * BB,
                                            (float)a00, (float)a01, (float)a10, (float)a11);
    k_gemm<<<dim3(128, 4), 512, 98304, stream>>>(Qall, W1qT, cvec, W2, out);
}